// Round 5
// baseline (267.328 us; speedup 1.0000x reference)
//
#include <hip/hip_runtime.h>
#include <hip/hip_bf16.h>

#define HWSZ 12544   // 112*112
#define WDIM 112
#define CIN  128
#define NPIX 25088   // B*HWSZ, B=2
#define VTROW 6272   // 112*56 = one (b,parity,ch) plane of vt (hw>>1 indexed)
#define VTOFF (2 * (size_t)NPIX * 64)   // vt base in qkv (u16 units)

typedef __attribute__((ext_vector_type(8))) short          short8;
typedef __attribute__((ext_vector_type(4))) float          float4v;
typedef __attribute__((ext_vector_type(4))) unsigned short ushort4v;

// NATTEN window start for K=7, D=2
__device__ __forceinline__ int window_start7x2(int idx, int L) {
    int ni = idx - 6;
    int imodd = idx & 1;
    int a = (L >> 1) << 1;
    int bb = L - a;
    int right = (imodd < bb) ? (L - bb + imodd - 12) : (a + imodd - 14);
    if (ni < 0) return imodd;
    if (idx + 6 >= L) return right;
    return ni;
}

__device__ __forceinline__ unsigned short f2bf(float f) {
    __hip_bfloat16 h = __float2bfloat16(f);
    return *(unsigned short*)&h;
}

// ---------------------------------------------------------------------------
// Projection GEMM body (identical math to rounds 1-4; ~8.3 us/launch).
// ---------------------------------------------------------------------------
__device__ __forceinline__ void proj_body(
    const float* __restrict__ x,
    const float* __restrict__ Wq, const float* __restrict__ bq,
    const float* __restrict__ Wk, const float* __restrict__ bk,
    const float* __restrict__ Wv, const float* __restrict__ bv,
    unsigned short* __restrict__ qbuf, int tile)
{
    __shared__ __align__(16) unsigned short wsb[3][64][136];   // [m][out][c], pad 8
    __shared__ __align__(16) unsigned short trans[64 * 80];    // epilogue transpose

    const int t = threadIdx.x, lane = t & 63, wv = t >> 6, quad = lane >> 4;
    const int col = lane & 15;

    const int pix0 = tile * 64;                 // HWSZ % 64 == 0: no b-straddle
    const int b    = tile / 196;
    const int hw0  = pix0 - b * HWSZ;
    const float* xb = x + (size_t)b * CIN * HWSZ;

    // stage all three W tiles [m][out][c] (fp32 -> bf16)
    #pragma unroll
    for (int m = 0; m < 3; ++m) {
        const float* Wm = (m == 0) ? Wq : (m == 1) ? Wk : Wv;
        #pragma unroll
        for (int i = 0; i < 8; ++i) {
            int u = t + 256 * i;
            int o = u >> 5, cq = (u & 31) * 4;
            float4 w4 = *(const float4*)&Wm[o * 128 + cq];
            ushort4v s4 = { f2bf(w4.x), f2bf(w4.y), f2bf(w4.z), f2bf(w4.w) };
            *(ushort4v*)&wsb[m][o][cq] = s4;
        }
    }

    // A-fragments direct from global: px = wv*16+col, ch = kc*32+quad*8+j
    const int hwpx = hw0 + wv * 16 + col;
    short8 af[4];
    #pragma unroll
    for (int kc = 0; kc < 4; ++kc) {
        #pragma unroll
        for (int j = 0; j < 8; ++j) {
            int c = kc * 32 + quad * 8 + j;
            af[kc][j] = (short)f2bf(xb[(size_t)c * HWSZ + hwpx]);
        }
    }
    __syncthreads();

    float4v acc[3][4];
    #pragma unroll
    for (int m = 0; m < 3; ++m)
        #pragma unroll
        for (int nt = 0; nt < 4; ++nt)
            acc[m][nt] = (float4v){0, 0, 0, 0};

    #pragma unroll
    for (int kc = 0; kc < 4; ++kc) {
        #pragma unroll
        for (int m = 0; m < 3; ++m) {
            #pragma unroll
            for (int nt = 0; nt < 4; ++nt) {
                short8 bfv = *(const short8*)&wsb[m][nt * 16 + col][kc * 32 + quad * 8];
                acc[m][nt] = __builtin_amdgcn_mfma_f32_16x16x32_bf16(af[kc], bfv, acc[m][nt], 0, 0, 0);
            }
        }
    }
    __syncthreads();   // wsb dead; trans about to be written

    // ---- q and k epilogues (natural [pix][64] layout), sequential via trans
    #pragma unroll
    for (int m = 0; m < 2; ++m) {
        const float scale = (m == 0) ? 0.125f : 1.0f;   // fold 64^-0.5 into q
        const float* bm = (m == 0) ? bq : bk;
        #pragma unroll
        for (int nt = 0; nt < 4; ++nt) {
            float bias = bm[nt * 16 + col];
            #pragma unroll
            for (int r = 0; r < 4; ++r) {
                int px = wv * 16 + quad * 4 + r;    // D: row = quad*4 + reg
                trans[px * 80 + nt * 16 + col] = f2bf((acc[m][nt][r] + bias) * scale);
            }
        }
        __syncthreads();
        unsigned short* outm = qbuf + (size_t)m * NPIX * 64;
        const int tpx = t >> 2, chunk = t & 3;
        const unsigned short* src = &trans[tpx * 80 + chunk * 16];
        unsigned short* dst = outm + (size_t)(pix0 + tpx) * 64 + chunk * 16;
        *(short8*)(dst)     = *(const short8*)(src);
        *(short8*)(dst + 8) = *(const short8*)(src + 8);
        __syncthreads();   // trans dead before next rewrite
    }

    // ---- v epilogue: stage [ch][parity*40 + px>>1], pitch 80
    {
        #pragma unroll
        for (int nt = 0; nt < 4; ++nt) {
            int ch = nt * 16 + col;
            float bias = bv[ch];
            #pragma unroll
            for (int r = 0; r < 4; ++r) {
                int px = wv * 16 + quad * 4 + r;
                trans[ch * 80 + (px & 1) * 40 + (px >> 1)] = f2bf(acc[2][nt][r] + bias);
            }
        }
        __syncthreads();
        unsigned short* vt = qbuf + VTOFF;
        const int ch = t >> 2, parity = (t >> 1) & 1, half = t & 1;
        const unsigned short* src = &trans[ch * 80 + parity * 40 + half * 16];
        // hw>>1 is continuous across h rows: no straddle, ever
        unsigned short* dst = vt + (size_t)((b * 2 + parity) * 64 + ch) * VTROW
                            + (hw0 >> 1) + half * 16;
        *(short8*)(dst)     = *(const short8*)(src);
        *(short8*)(dst + 8) = *(const short8*)(src + 8);
    }
}

__global__ __launch_bounds__(256) void proj_mfma(
    const float* __restrict__ x,
    const float* __restrict__ Wq, const float* __restrict__ bq,
    const float* __restrict__ Wk, const float* __restrict__ bk,
    const float* __restrict__ Wv, const float* __restrict__ bv,
    unsigned short* __restrict__ qbuf)
{
    proj_body(x, Wq, bq, Wk, bk, Wv, bv, qbuf, blockIdx.x);
}

// DIAGNOSTIC: 8x rep with laundered pointers (defeats LICM; each rep fully
// re-executes). Bit-idempotent: rewrites identical bytes. Surfaces in the
// top-5 counter table (dur ~66 us > 44 us fills).
__global__ __launch_bounds__(256) void proj_rep(
    const float* __restrict__ x,
    const float* __restrict__ Wq, const float* __restrict__ bq,
    const float* __restrict__ Wk, const float* __restrict__ bk,
    const float* __restrict__ Wv, const float* __restrict__ bv,
    unsigned short* __restrict__ qbuf)
{
    for (int rep = 0; rep < 8; ++rep) {
        const float* xr = x;
        unsigned short* qr = qbuf;
        asm volatile("" : "+v"(xr), "+v"(qr) :: "memory");
        proj_body(xr, Wq, bq, Wk, bk, Wv, bv, qr, blockIdx.x);
        __syncthreads();
    }
}

// ---------------------------------------------------------------------------
// Attention v2 body (identical math to round 4; ~19-21 us/launch).
// 4-wave blocks: (w-parity g) x (work-half vh); unnormalized-P split with
// deferred softmax divide.
// ---------------------------------------------------------------------------
__device__ __forceinline__ void attn_body(
    const unsigned short* __restrict__ qkv, float* __restrict__ out, int bx)
{
    __shared__ __align__(16) unsigned short ps[2][16 * 232]; // [g][px][u], block-shared
    __shared__ __align__(16) float sums_lds[2][2][16];       // [g][vh][row]
    __shared__ __align__(16) float lds_out[64 * 36];         // [ch][w_local]

    const int tid  = threadIdx.x;
    const int lane = tid & 63, wid = tid >> 6;
    const int g    = wid & 1;        // w-parity
    const int vh   = wid >> 1;       // work half
    const int quad = lane >> 4, col = lane & 15;

    const int xcd  = bx & 7;
    const int idx  = bx >> 3;                    // 0..111
    const int h    = xcd * 14 + (idx >> 3);
    const int b    = (idx >> 2) & 1;
    const int sub  = idx & 3;
    const int pb   = (sub < 3) ? sub * 16 : 40;  // last tile overlaps (benign)

    const int hs  = window_start7x2(h, WDIM);
    const int ws0 = window_start7x2(2 * pb + g, WDIM);
    const int cb0 = (ws0 >> 1) & ~7;             // 8-aligned col base
    const int pixbase = b * HWSZ;

    const unsigned short* qg = qkv;
    const unsigned short* kg = qkv + (size_t)NPIX * 64;
    const unsigned short* vt = qkv + VTOFF + (size_t)(b * 2 + g) * 64 * VTROW;

    // ---- Q A-fragments (m = col = px, k = ch); q pre-scaled by 0.125
    const int qpix = pixbase + h * WDIM + 2 * (pb + col) + g;
    short8 af0 = *(const short8*)(qg + (size_t)qpix * 64 + quad * 8);
    short8 af1 = *(const short8*)(qg + (size_t)qpix * 64 + 32 + quad * 8);

    // per-lane window col bases (relative to cb0) for rows px = quad*4 + r
    int cbr[4];
    #pragma unroll
    for (int r = 0; r < 4; ++r)
        cbr[r] = (window_start7x2(2 * (pb + quad * 4 + r) + g, WDIM) >> 1) - cb0;

    // V-row offsets; prefetch this wave's ch-half (7 kc x 2 nt)
    int rowoff[7];
    #pragma unroll
    for (int kc = 0; kc < 7; ++kc) {
        int u8 = kc * 32 + quad * 8;
        rowoff[kc] = (hs + 2 * (u8 >> 5)) * 56 + cb0 + (u8 & 31);  // 16B aligned
    }
    short8 vpre[7][2];
    #pragma unroll
    for (int kc = 0; kc < 7; ++kc)
        #pragma unroll
        for (int ntl = 0; ntl < 2; ++ntl)
            vpre[kc][ntl] = *(const short8*)
                (vt + (size_t)(vh * 32 + ntl * 16 + col) * VTROW + rowoff[kc]);

    // ---- scores: this wave's 7 n-tiles (of 14), K-dim = 64 ch
    float4v S[7];
    #pragma unroll
    for (int ntl = 0; ntl < 7; ++ntl) {
        int ntg = vh * 7 + ntl;
        int u = ntg * 16 + col;
        int i = u >> 5, c = u & 31;
        int wcol = cb0 + c;
        int kw = 2 * wcol + g; kw = (kw > 111) ? 111 : kw;   // addr guard
        int kp = pixbase + (hs + 2 * i) * WDIM + kw;
        float4v a = {0, 0, 0, 0};
        __builtin_amdgcn_s_setprio(1);
        a = __builtin_amdgcn_mfma_f32_16x16x32_bf16(
                af0, *(const short8*)(kg + (size_t)kp * 64 + quad * 8), a, 0, 0, 0);
        a = __builtin_amdgcn_mfma_f32_16x16x32_bf16(
                af1, *(const short8*)(kg + (size_t)kp * 64 + 32 + quad * 8), a, 0, 0, 0);
        __builtin_amdgcn_s_setprio(0);
        bool colok = (wcol <= 55);
        #pragma unroll
        for (int r = 0; r < 4; ++r) {
            bool valid = colok && ((unsigned)(c - cbr[r]) < 7u);
            S[ntl][r] = valid ? a[r] : -1e30f;
        }
    }

    // ---- exp + partial row-sums; write UNNORMALIZED P (masked -> exp = 0)
    float psum[4];
    #pragma unroll
    for (int r = 0; r < 4; ++r) {
        float sum = 0.0f;
        #pragma unroll
        for (int ntl = 0; ntl < 7; ++ntl) {
            float e = __expf(S[ntl][r]);
            S[ntl][r] = e;
            sum += e;
        }
        #pragma unroll
        for (int msk = 1; msk < 16; msk <<= 1)
            sum += __shfl_xor(sum, msk, 64);
        psum[r] = sum;
        int row = quad * 4 + r;
        #pragma unroll
        for (int ntl = 0; ntl < 7; ++ntl)
            ps[g][row * 232 + (vh * 7 + ntl) * 16 + col] = f2bf(S[ntl][r]);
    }
    if (col == 0) {
        #pragma unroll
        for (int r = 0; r < 4; ++r)
            sums_lds[g][vh][quad * 4 + r] = psum[r];
    }
    __syncthreads();   // P halves + partial sums visible block-wide

    float rinv[4];
    #pragma unroll
    for (int r = 0; r < 4; ++r) {
        int row = quad * 4 + r;
        rinv[r] = 1.0f / (sums_lds[g][0][row] + sums_lds[g][1][row]);
    }

    // ---- PV: O[16][32] = P(16x224) * V(224x32)  (this wave's ch-half)
    float4v O[2] = {{0,0,0,0},{0,0,0,0}};
    #pragma unroll
    for (int kc = 0; kc < 7; ++kc) {
        short8 pa = *(const short8*)&ps[g][col * 232 + kc * 32 + quad * 8];
        __builtin_amdgcn_s_setprio(1);
        #pragma unroll
        for (int ntl = 0; ntl < 2; ++ntl)
            O[ntl] = __builtin_amdgcn_mfma_f32_16x16x32_bf16(pa, vpre[kc][ntl], O[ntl], 0, 0, 0);
        __builtin_amdgcn_s_setprio(0);
    }

    // ---- epilogue: normalize (deferred softmax divide) + stage to LDS
    #pragma unroll
    for (int ntl = 0; ntl < 2; ++ntl) {
        int ch = vh * 32 + ntl * 16 + col;
        #pragma unroll
        for (int r = 0; r < 4; ++r)
            lds_out[ch * 36 + 2 * (quad * 4 + r) + g] = O[ntl][r] * rinv[r];
    }
    __syncthreads();

    // contiguous writes: out[b][ch][h][2pb .. 2pb+32), 256 threads
    {
        const int ch = tid >> 2, q4 = tid & 3;
        float* ob = out + (size_t)(b * 64 + ch) * HWSZ + h * WDIM + 2 * pb + q4 * 8;
        const float* src = &lds_out[ch * 36 + q4 * 8];
        *(float4*)(ob)     = *(const float4*)(src);
        *(float4*)(ob + 4) = *(const float4*)(src + 4);
    }
}

__global__ __launch_bounds__(256) void attn_mfma(
    const unsigned short* __restrict__ qkv, float* __restrict__ out)
{
    attn_body(qkv, out, blockIdx.x);
}

// DIAGNOSTIC: 8x rep, laundered pointers. Race-free across reps (every
// cross-wave LDS buffer reuse is separated by a barrier: ps/sums_lds by the
// final epilogue barrier, lds_out by the next rep's mid barrier).
// Bit-idempotent. Surfaces in top-5 (~150 us) with full SQ counters.
__global__ __launch_bounds__(256) void attn_rep(
    const unsigned short* __restrict__ qkv, float* __restrict__ out)
{
    for (int rep = 0; rep < 8; ++rep) {
        const unsigned short* qr = qkv;
        float* orr = out;
        asm volatile("" : "+v"(qr), "+v"(orr) :: "memory");
        attn_body(qr, orr, blockIdx.x);
        __syncthreads();
    }
}

// ---------------------------------------------------------------------------
extern "C" void kernel_launch(void* const* d_in, const int* in_sizes, int n_in,
                              void* d_out, int out_size, void* d_ws, size_t ws_size,
                              hipStream_t stream) {
    const float* x  = (const float*)d_in[0];
    const float* Wq = (const float*)d_in[1];
    const float* bq = (const float*)d_in[2];
    const float* Wk = (const float*)d_in[3];
    const float* bk = (const float*)d_in[4];
    const float* Wv = (const float*)d_in[5];
    const float* bv = (const float*)d_in[6];
    float* out = (float*)d_out;

    // ws: q [NPIX][64] | k [NPIX][64] | vt [256][VTROW]  (u16)
    unsigned short* qkv = (unsigned short*)d_ws;

    // real pipeline
    proj_mfma<<<dim3(392), dim3(256), 0, stream>>>(x, Wq, bq, Wk, bk, Wv, bv, qkv);
    attn_mfma<<<dim3(896), dim3(256), 0, stream>>>(qkv, out);

    // diagnostic rep-dispatches (idempotent rewrites; surface our kernels'
    // counters in the top-5 table, which otherwise only shows >41us fills)
    proj_rep<<<dim3(392), dim3(256), 0, stream>>>(x, Wq, bq, Wk, bk, Wv, bv, qkv);
    attn_rep<<<dim3(896), dim3(256), 0, stream>>>(qkv, out);
}

// Round 6
// 225.101 us; speedup vs baseline: 1.1876x; 1.1876x over previous
//
#include <hip/hip_runtime.h>
#include <hip/hip_bf16.h>

#define HWSZ 12544   // 112*112
#define WDIM 112
#define CIN  128
#define NPIX 25088   // B*HWSZ, B=2
#define VTROW 6272   // 112*56 = one (b,parity,ch) plane of vt (hw>>1 indexed)
#define VTOFF (2 * (size_t)NPIX * 64)   // vt base in qkv (u16 units)

typedef __attribute__((ext_vector_type(8))) short          short8;
typedef __attribute__((ext_vector_type(4))) float          float4v;
typedef __attribute__((ext_vector_type(4))) unsigned short ushort4v;

#define AS1 __attribute__((address_space(1)))
#define AS3 __attribute__((address_space(3)))

// async 16B global->LDS: per-lane global src, wave-uniform LDS base,
// HW writes lane i at base + i*16 (m104). Tracked by vmcnt.
__device__ __forceinline__ void gload_lds16(const void* g, void* l) {
    __builtin_amdgcn_global_load_lds((const AS1 unsigned int*)g,
                                     (AS3 unsigned int*)l, 16, 0, 0);
}

// NATTEN window start for K=7, D=2
__device__ __forceinline__ int window_start7x2(int idx, int L) {
    int ni = idx - 6;
    int imodd = idx & 1;
    int a = (L >> 1) << 1;
    int bb = L - a;
    int right = (imodd < bb) ? (L - bb + imodd - 12) : (a + imodd - 14);
    if (ni < 0) return imodd;
    if (idx + 6 >= L) return right;
    return ni;
}

__device__ __forceinline__ unsigned short f2bf(float f) {
    __hip_bfloat16 h = __float2bfloat16(f);
    return *(unsigned short*)&h;
}

// ---------------------------------------------------------------------------
// Projection GEMM — unchanged (measured ~8.3 us/launch).
// ---------------------------------------------------------------------------
__global__ __launch_bounds__(256) void proj_mfma(
    const float* __restrict__ x,
    const float* __restrict__ Wq, const float* __restrict__ bq,
    const float* __restrict__ Wk, const float* __restrict__ bk,
    const float* __restrict__ Wv, const float* __restrict__ bv,
    unsigned short* __restrict__ qbuf)
{
    __shared__ __align__(16) unsigned short wsb[3][64][136];   // [m][out][c], pad 8
    __shared__ __align__(16) unsigned short trans[64 * 80];    // epilogue transpose

    const int t = threadIdx.x, lane = t & 63, wv = t >> 6, quad = lane >> 4;
    const int col = lane & 15;

    const int tile = blockIdx.x;                // 0..391
    const int pix0 = tile * 64;                 // HWSZ % 64 == 0: no b-straddle
    const int b    = tile / 196;
    const int hw0  = pix0 - b * HWSZ;
    const float* xb = x + (size_t)b * CIN * HWSZ;

    #pragma unroll
    for (int m = 0; m < 3; ++m) {
        const float* Wm = (m == 0) ? Wq : (m == 1) ? Wk : Wv;
        #pragma unroll
        for (int i = 0; i < 8; ++i) {
            int u = t + 256 * i;
            int o = u >> 5, cq = (u & 31) * 4;
            float4 w4 = *(const float4*)&Wm[o * 128 + cq];
            ushort4v s4 = { f2bf(w4.x), f2bf(w4.y), f2bf(w4.z), f2bf(w4.w) };
            *(ushort4v*)&wsb[m][o][cq] = s4;
        }
    }

    const int hwpx = hw0 + wv * 16 + col;
    short8 af[4];
    #pragma unroll
    for (int kc = 0; kc < 4; ++kc) {
        #pragma unroll
        for (int j = 0; j < 8; ++j) {
            int c = kc * 32 + quad * 8 + j;
            af[kc][j] = (short)f2bf(xb[(size_t)c * HWSZ + hwpx]);
        }
    }
    __syncthreads();

    float4v acc[3][4];
    #pragma unroll
    for (int m = 0; m < 3; ++m)
        #pragma unroll
        for (int nt = 0; nt < 4; ++nt)
            acc[m][nt] = (float4v){0, 0, 0, 0};

    #pragma unroll
    for (int kc = 0; kc < 4; ++kc) {
        #pragma unroll
        for (int m = 0; m < 3; ++m) {
            #pragma unroll
            for (int nt = 0; nt < 4; ++nt) {
                short8 bfv = *(const short8*)&wsb[m][nt * 16 + col][kc * 32 + quad * 8];
                acc[m][nt] = __builtin_amdgcn_mfma_f32_16x16x32_bf16(af[kc], bfv, acc[m][nt], 0, 0, 0);
            }
        }
    }
    __syncthreads();

    #pragma unroll
    for (int m = 0; m < 2; ++m) {
        const float scale = (m == 0) ? 0.125f : 1.0f;
        const float* bm = (m == 0) ? bq : bk;
        #pragma unroll
        for (int nt = 0; nt < 4; ++nt) {
            float bias = bm[nt * 16 + col];
            #pragma unroll
            for (int r = 0; r < 4; ++r) {
                int px = wv * 16 + quad * 4 + r;
                trans[px * 80 + nt * 16 + col] = f2bf((acc[m][nt][r] + bias) * scale);
            }
        }
        __syncthreads();
        unsigned short* outm = qbuf + (size_t)m * NPIX * 64;
        const int tpx = t >> 2, chunk = t & 3;
        const unsigned short* src = &trans[tpx * 80 + chunk * 16];
        unsigned short* dst = outm + (size_t)(pix0 + tpx) * 64 + chunk * 16;
        *(short8*)(dst)     = *(const short8*)(src);
        *(short8*)(dst + 8) = *(const short8*)(src + 8);
        __syncthreads();
    }

    {
        #pragma unroll
        for (int nt = 0; nt < 4; ++nt) {
            int ch = nt * 16 + col;
            float bias = bv[ch];
            #pragma unroll
            for (int r = 0; r < 4; ++r) {
                int px = wv * 16 + quad * 4 + r;
                trans[ch * 80 + (px & 1) * 40 + (px >> 1)] = f2bf(acc[2][nt][r] + bias);
            }
        }
        __syncthreads();
        unsigned short* vt = qbuf + VTOFF;
        const int ch = t >> 2, parity = (t >> 1) & 1, half = t & 1;
        const unsigned short* src = &trans[ch * 80 + parity * 40 + half * 16];
        unsigned short* dst = vt + (size_t)((b * 2 + parity) * 64 + ch) * VTROW
                            + (hw0 >> 1) + half * 16;
        *(short8*)(dst)     = *(const short8*)(src);
        *(short8*)(dst + 8) = *(const short8*)(src + 8);
    }
}

// ---------------------------------------------------------------------------
// Attention v3 — async K staging via global_load_lds.
// R4 counters showed latency-bound (VALU 12%, Mfma 4%, Occ 18%, all
// L2/L3-resident): 92 VGPRs forced serial ~600cy loads. Now each wave's 14
// K-fragments stream async into a linear LDS slab (identical per-lane
// addresses -> bit-identical operands), V prefetch stays in regs (fits now),
// so ALL global traffic is in flight concurrently; one vmcnt(0) pays a
// single latency period. ps/lds_out overlay dead slabs (57.6KB static).
// setprio removed (m190). grid 896 x 256.
// ---------------------------------------------------------------------------
__device__ __forceinline__ void attn_body(
    const unsigned short* __restrict__ qkv, float* __restrict__ out, int bx)
{
    __shared__ __align__(16) unsigned char slab[4][14336]; // [wave][7 tiles x 2KB]
    __shared__ __align__(16) float sums_lds[2][2][16];     // [g][vh][row]

    const int tid  = threadIdx.x;
    const int lane = tid & 63, wid = tid >> 6;
    const int g    = wid & 1;        // w-parity
    const int vh   = wid >> 1;       // work half
    const int quad = lane >> 4, col = lane & 15;

    const int xcd  = bx & 7;
    const int idx  = bx >> 3;                    // 0..111
    const int h    = xcd * 14 + (idx >> 3);
    const int b    = (idx >> 2) & 1;
    const int sub  = idx & 3;
    const int pb   = (sub < 3) ? sub * 16 : 40;  // last tile overlaps (benign)

    const int hs  = window_start7x2(h, WDIM);
    const int ws0 = window_start7x2(2 * pb + g, WDIM);
    const int cb0 = (ws0 >> 1) & ~7;             // 8-aligned col base
    const int pixbase = b * HWSZ;

    const unsigned short* qg = qkv;
    const unsigned short* kg = qkv + (size_t)NPIX * 64;
    const unsigned short* vt = qkv + VTOFF + (size_t)(b * 2 + g) * 64 * VTROW;

    unsigned short* ps_g   = (unsigned short*)slab[g];   // overlay: waves 0/1 slabs
    unsigned char*  myslab = slab[wid];

    // ---- Q A-fragments (direct; sector-efficient)
    const int qpix = pixbase + h * WDIM + 2 * (pb + col) + g;
    short8 af0 = *(const short8*)(qg + (size_t)qpix * 64 + quad * 8);
    short8 af1 = *(const short8*)(qg + (size_t)qpix * 64 + 32 + quad * 8);

    // per-lane window col bases (relative to cb0) for rows px = quad*4 + r
    int cbr[4];
    #pragma unroll
    for (int r = 0; r < 4; ++r)
        cbr[r] = (window_start7x2(2 * (pb + quad * 4 + r) + g, WDIM) >> 1) - cb0;

    // V-row offsets + register prefetch of this wave's ch-half (7 kc x 2 nt)
    int rowoff[7];
    #pragma unroll
    for (int kc = 0; kc < 7; ++kc) {
        int u8 = kc * 32 + quad * 8;
        rowoff[kc] = (hs + 2 * (u8 >> 5)) * 56 + cb0 + (u8 & 31);  // 16B aligned
    }
    short8 vpre[7][2];
    #pragma unroll
    for (int kc = 0; kc < 7; ++kc)
        #pragma unroll
        for (int ntl = 0; ntl < 2; ++ntl)
            vpre[kc][ntl] = *(const short8*)
                (vt + (size_t)(vh * 32 + ntl * 16 + col) * VTROW + rowoff[kc]);

    // ---- async K staging: 14 x global_load_lds into own slab (zero VGPR)
    #pragma unroll
    for (int ntl = 0; ntl < 7; ++ntl) {
        int u = (vh * 7 + ntl) * 16 + col;
        int i = u >> 5, c = u & 31;
        int kw = 2 * (cb0 + c) + g; kw = (kw > 111) ? 111 : kw;   // addr guard
        int kp = pixbase + (hs + 2 * i) * WDIM + kw;
        const unsigned short* gs = kg + (size_t)kp * 64 + quad * 8;
        gload_lds16(gs,      myslab + ntl * 2048);
        gload_lds16(gs + 32, myslab + ntl * 2048 + 1024);
    }

    // one latency period for everything in flight (K stages + vpre + Q)
    asm volatile("s_waitcnt vmcnt(0)" ::: "memory");
    __builtin_amdgcn_sched_barrier(0);

    // ---- scores: 7 n-tiles from own slab (conflict-free lane*16 reads)
    float4v S[7];
    #pragma unroll
    for (int ntl = 0; ntl < 7; ++ntl) {
        short8 b0 = *(const short8*)(myslab + ntl * 2048 + lane * 16);
        short8 b1 = *(const short8*)(myslab + ntl * 2048 + 1024 + lane * 16);
        float4v a = {0, 0, 0, 0};
        a = __builtin_amdgcn_mfma_f32_16x16x32_bf16(af0, b0, a, 0, 0, 0);
        a = __builtin_amdgcn_mfma_f32_16x16x32_bf16(af1, b1, a, 0, 0, 0);
        int u = (vh * 7 + ntl) * 16 + col;
        int c = u & 31;
        bool colok = (cb0 + c <= 55);
        #pragma unroll
        for (int r = 0; r < 4; ++r) {
            bool valid = colok && ((unsigned)(c - cbr[r]) < 7u);
            S[ntl][r] = valid ? a[r] : -1e30f;
        }
    }

    // ---- exp + partial row-sums (regs only; masked -> exp = 0)
    float psum[4];
    #pragma unroll
    for (int r = 0; r < 4; ++r) {
        float sum = 0.0f;
        #pragma unroll
        for (int ntl = 0; ntl < 7; ++ntl) {
            float e = __expf(S[ntl][r]);
            S[ntl][r] = e;
            sum += e;
        }
        #pragma unroll
        for (int msk = 1; msk < 16; msk <<= 1)
            sum += __shfl_xor(sum, msk, 64);
        psum[r] = sum;
    }

    __syncthreads();   // all slab score-reads done; slabs 0/1 reusable as ps

    // ---- write UNNORMALIZED P + partial sums
    #pragma unroll
    for (int r = 0; r < 4; ++r) {
        int row = quad * 4 + r;
        #pragma unroll
        for (int ntl = 0; ntl < 7; ++ntl)
            ps_g[row * 232 + (vh * 7 + ntl) * 16 + col] = f2bf(S[ntl][r]);
    }
    if (col == 0) {
        #pragma unroll
        for (int r = 0; r < 4; ++r)
            sums_lds[g][vh][quad * 4 + r] = psum[r];
    }
    __syncthreads();   // P + sums visible block-wide

    float rinv[4];
    #pragma unroll
    for (int r = 0; r < 4; ++r) {
        int row = quad * 4 + r;
        rinv[r] = 1.0f / (sums_lds[g][0][row] + sums_lds[g][1][row]);
    }

    // ---- PV: O[16][32] = P(16x224) * V(224x32)  (this wave's ch-half)
    float4v O[2] = {{0,0,0,0},{0,0,0,0}};
    #pragma unroll
    for (int kc = 0; kc < 7; ++kc) {
        short8 pa = *(const short8*)&ps_g[col * 232 + kc * 32 + quad * 8];
        #pragma unroll
        for (int ntl = 0; ntl < 2; ++ntl)
            O[ntl] = __builtin_amdgcn_mfma_f32_16x16x32_bf16(pa, vpre[kc][ntl], O[ntl], 0, 0, 0);
    }

    // ---- epilogue: deferred softmax divide; stage to lds_out (slab 2 overlay)
    float* lds_out = (float*)slab[2];
    #pragma unroll
    for (int ntl = 0; ntl < 2; ++ntl) {
        int ch = vh * 32 + ntl * 16 + col;
        #pragma unroll
        for (int r = 0; r < 4; ++r)
            lds_out[ch * 36 + 2 * (quad * 4 + r) + g] = O[ntl][r] * rinv[r];
    }
    __syncthreads();

    // contiguous writes: out[b][ch][h][2pb .. 2pb+32), 256 threads
    {
        const int ch = tid >> 2, q4 = tid & 3;
        float* ob = out + (size_t)(b * 64 + ch) * HWSZ + h * WDIM + 2 * pb + q4 * 8;
        const float* src = &lds_out[ch * 36 + q4 * 8];
        *(float4*)(ob)     = *(const float4*)(src);
        *(float4*)(ob + 4) = *(const float4*)(src + 4);
    }
}

__global__ __launch_bounds__(256) void attn_mfma(
    const unsigned short* __restrict__ qkv, float* __restrict__ out)
{
    attn_body(qkv, out, blockIdx.x);
}

// DIAGNOSTIC: 8x rep, laundered pointers (defeats LICM). Bit-idempotent;
// rep-end barrier separates slab reuse across reps. Surfaces full counters.
__global__ __launch_bounds__(256) void attn_rep(
    const unsigned short* __restrict__ qkv, float* __restrict__ out)
{
    for (int rep = 0; rep < 8; ++rep) {
        const unsigned short* qr = qkv;
        float* orr = out;
        asm volatile("" : "+v"(qr), "+v"(orr) :: "memory");
        attn_body(qr, orr, blockIdx.x);
        __syncthreads();
    }
}

// ---------------------------------------------------------------------------
extern "C" void kernel_launch(void* const* d_in, const int* in_sizes, int n_in,
                              void* d_out, int out_size, void* d_ws, size_t ws_size,
                              hipStream_t stream) {
    const float* x  = (const float*)d_in[0];
    const float* Wq = (const float*)d_in[1];
    const float* bq = (const float*)d_in[2];
    const float* Wk = (const float*)d_in[3];
    const float* bk = (const float*)d_in[4];
    const float* Wv = (const float*)d_in[5];
    const float* bv = (const float*)d_in[6];
    float* out = (float*)d_out;

    // ws: q [NPIX][64] | k [NPIX][64] | vt [256][VTROW]  (u16)
    unsigned short* qkv = (unsigned short*)d_ws;

    proj_mfma<<<dim3(392), dim3(256), 0, stream>>>(x, Wq, bq, Wk, bk, Wv, bv, qkv);
    attn_mfma<<<dim3(896), dim3(256), 0, stream>>>(qkv, out);

    // diagnostic (removed once attn verdict is in)
    attn_rep<<<dim3(896), dim3(256), 0, stream>>>(qkv, out);
}